// Round 1
// baseline (36.994 us; speedup 1.0000x reference)
//
#include <hip/hip_runtime.h>
#include <math.h>

#define TILE 16
#define HALO 4
#define DT (TILE + HALO)   // 20
#define CPB 6              // colors per block
#define NCOL 30
#define HDIM 224
#define WDIM 224
#define OH 220
#define OW 220
#define NORM_INV (1.0f / (25.0f * 768.0f))

__global__ __launch_bounds__(256) void rgb_conv2d_kernel(
    const float* __restrict__ in,   // [B,3,224,224]
    const float* __restrict__ wt,   // [30,3,5,5] (color tiled over 5x5)
    float* __restrict__ out)        // [B,30,220,220]
{
    __shared__ float PR[DT * DT];
    __shared__ float PG[DT * DT];
    __shared__ float PB[DT * DT];
    __shared__ float Dd[DT * DT];
    __shared__ float Hh[DT * TILE];

    const int tid = threadIdx.x;
    const int tx = tid & 15;
    const int ty = tid >> 4;

    const int bx = blockIdx.x;           // 0..13
    const int by = blockIdx.y;           // 0..13
    const int bz = blockIdx.z;           // b * (NCOL/CPB) + colorgroup
    const int b  = bz / (NCOL / CPB);
    const int g  = bz % (NCOL / CPB);

    const int x0 = bx * TILE;
    const int y0 = by * TILE;

    const float* inb = in + (size_t)b * 3 * HDIM * WDIM;

    // Load pixel tile (clamped at edges; clamped texels only feed
    // out-of-range outputs which are never written), pre-scaled by 255.
    for (int idx = tid; idx < DT * DT; idx += 256) {
        int yy = idx / DT, xx = idx - yy * DT;
        int gy = min(y0 + yy, HDIM - 1);
        int gx = min(x0 + xx, WDIM - 1);
        int o = gy * WDIM + gx;
        PR[idx] = inb[o] * 255.0f;
        PG[idx] = inb[HDIM * WDIM + o] * 255.0f;
        PB[idx] = inb[2 * HDIM * WDIM + o] * 255.0f;
    }

    for (int ci = 0; ci < CPB; ++ci) {
        const int c = g * CPB + ci;
        // weight[c, ch, 0, 0]; all 25 taps are identical per (c, ch)
        const float R2 = wt[c * 75 +  0] * 255.0f;
        const float G2 = wt[c * 75 + 25] * 255.0f;
        const float B2 = wt[c * 75 + 50] * 255.0f;

        __syncthreads();  // pixel tile ready / previous H fully consumed

        // Per-pixel distance map D (20x20)
        for (int idx = tid; idx < DT * DT; idx += 256) {
            float R1 = PR[idx], G1 = PG[idx], B1 = PB[idx];
            float dR = R1 - R2;
            float dG = G1 - G2;
            float dB = B1 - B2;
            float rmean = (R1 + R2) * 0.5f;
            float cR = 2.0f + rmean * (1.0f / 256.0f);
            float cB = 2.0f + (255.0f - rmean) * (1.0f / 256.0f);
            Dd[idx] = sqrtf(cR * dR * dR + 4.0f * dG * dG + cB * dB * dB + 1e-8f);
        }
        __syncthreads();

        // Horizontal 5-sum: H[20][16]
        for (int idx = tid; idx < DT * TILE; idx += 256) {
            int yy = idx >> 4, xx = idx & 15;
            const float* row = &Dd[yy * DT + xx];
            Hh[idx] = row[0] + row[1] + row[2] + row[3] + row[4];
        }
        __syncthreads();

        // Vertical 5-sum + write
        const int oy = y0 + ty, ox = x0 + tx;
        if (oy < OH && ox < OW) {
            float s = Hh[ty * TILE + tx]
                    + Hh[(ty + 1) * TILE + tx]
                    + Hh[(ty + 2) * TILE + tx]
                    + Hh[(ty + 3) * TILE + tx]
                    + Hh[(ty + 4) * TILE + tx];
            out[(((size_t)b * NCOL + c) * OH + oy) * OW + ox] = s * NORM_INV;
        }
    }
}

extern "C" void kernel_launch(void* const* d_in, const int* in_sizes, int n_in,
                              void* d_out, int out_size, void* d_ws, size_t ws_size,
                              hipStream_t stream) {
    const float* in = (const float*)d_in[0];
    const float* wt = (const float*)d_in[1];
    float* out = (float*)d_out;

    const int B = in_sizes[0] / (3 * HDIM * WDIM);   // 8
    dim3 grid((OW + TILE - 1) / TILE, (OH + TILE - 1) / TILE, B * (NCOL / CPB));
    rgb_conv2d_kernel<<<grid, dim3(256), 0, stream>>>(in, wt, out);
}

// Round 2
// 24.382 us; speedup vs baseline: 1.5173x; 1.5173x over previous
//
#include <hip/hip_runtime.h>
#include <math.h>

#define NCOL 30
#define CPB 6              // colors per block (grid.z = B * 5)
#define HDIM 224
#define WDIM 224
#define OH 220
#define OW 220
#define TX 64              // output tile width
#define TY 16              // output tile height
#define DX 68              // input tile width  (TX + 4)
#define DY 20              // input tile height (TY + 4)
#define ND (DX * DY)       // 1360 = 5*256 + 80
#define NH (TX * DY)       // 1280 = 5*256
#define NORM_INV (1.0f / (25.0f * 768.0f))

__global__ __launch_bounds__(256) void rgb_conv2d_kernel(
    const float* __restrict__ in,   // [B,3,224,224]
    const float* __restrict__ wt,   // [30,3,5,5] (color constant over the 5x5 window)
    float* __restrict__ out)        // [B,30,220,220]
{
    __shared__ float Dd[ND];        // per-pixel distance tile, row stride DX, stored linearly
    __shared__ float Hh[NH];        // horizontal 5-sums, row stride TX

    const int tid = threadIdx.x;
    const int bx = blockIdx.x;           // 0..3
    const int by = blockIdx.y;           // 0..13
    const int bz = blockIdx.z;           // b*5 + colorgroup
    const int b  = bz / 5;
    const int g  = bz - 5 * b;

    // Shift edge tiles so every output lane is valid (overlap region writes
    // identical values twice — deterministic, benign).
    const int x0 = (bx < 3) ? bx * TX : (OW - TX);   // {0,64,128,156}
    const int y0 = (by < 13) ? by * TY : (OH - TY);  // {0,16,...,192,204}

    const float* inb = in + (size_t)b * 3 * HDIM * WDIM;

    // ---- Load pixel tile into REGISTERS (pre-scaled x255), reused for 6 colors.
    // Linear index idx = tid + p*256 over the DY x DX tile.
    float R1[6], G1[6], B1[6];
    #pragma unroll
    for (int p = 0; p < 6; ++p) {
        int idx = tid + p * 256;
        if (idx < ND) {
            int row = idx / DX;
            int col = idx - row * DX;
            int o = (y0 + row) * WDIM + (x0 + col);
            R1[p] = inb[o] * 255.0f;
            G1[p] = inb[HDIM * WDIM + o] * 255.0f;
            B1[p] = inb[2 * HDIM * WDIM + o] * 255.0f;
        }
    }

    const int tx = tid & 63;
    const int ty = tid >> 6;

    for (int ci = 0; ci < CPB; ++ci) {
        const int c = g * CPB + ci;
        const float R2 = wt[c * 75 +  0] * 255.0f;
        const float G2 = wt[c * 75 + 25] * 255.0f;
        const float B2 = wt[c * 75 + 50] * 255.0f;
        // d^2 = cR*dR^2 + 4*dG^2 + cB*dB^2 + eps,
        // cR = 2 + (R1+R2)/512 = fma(R1, 1/512, kR);  cB = (4 + 255/256) - cR
        const float kR = fmaf(R2, 1.0f / 512.0f, 2.0f);
        const float CC = 4.0f + 255.0f / 256.0f;

        __syncthreads();   // previous iteration's Hh fully consumed

        // ---- Per-pixel distance map, linear LDS writes (no address math)
        #pragma unroll
        for (int p = 0; p < 6; ++p) {
            int idx = tid + p * 256;
            if (idx < ND) {
                float r = R1[p], gg = G1[p], bb = B1[p];
                float cR = fmaf(r, 1.0f / 512.0f, kR);
                float cB = CC - cR;
                float dR = r - R2;
                float dG = gg - G2;
                float dB = bb - B2;
                float s = fmaf(cR * dR, dR, 1e-8f);
                s = fmaf(4.0f * dG, dG, s);
                s = fmaf(cB * dB, dB, s);
                Dd[idx] = __builtin_amdgcn_sqrtf(s);
            }
        }
        __syncthreads();

        // ---- Horizontal 5-sum: H[20][64], hidx = hrow*64+hcol, exactly 5 passes
        #pragma unroll
        for (int p = 0; p < 5; ++p) {
            int hidx = tid + p * 256;
            int daddr = hidx + ((hidx >> 6) << 2);  // hrow*68 + hcol
            Hh[hidx] = Dd[daddr] + Dd[daddr + 1] + Dd[daddr + 2]
                     + Dd[daddr + 3] + Dd[daddr + 4];
        }
        __syncthreads();

        // ---- Vertical 5-sum: thread owns rows 4ty..4ty+3 at column tx,
        // register sliding window over 8 H values.
        const float* hc = &Hh[(4 * ty) * TX + tx];
        float h0 = hc[0 * TX], h1 = hc[1 * TX], h2 = hc[2 * TX], h3 = hc[3 * TX];
        float h4 = hc[4 * TX], h5 = hc[5 * TX], h6 = hc[6 * TX], h7 = hc[7 * TX];
        float s0 = h0 + h1 + h2 + h3 + h4;
        float s1 = s0 - h0 + h5;
        float s2 = s1 - h1 + h6;
        float s3 = s2 - h2 + h7;

        float* ob = out + (((size_t)b * NCOL + c) * OH + (y0 + 4 * ty)) * OW + x0 + tx;
        ob[0 * OW] = s0 * NORM_INV;
        ob[1 * OW] = s1 * NORM_INV;
        ob[2 * OW] = s2 * NORM_INV;
        ob[3 * OW] = s3 * NORM_INV;
    }
}

extern "C" void kernel_launch(void* const* d_in, const int* in_sizes, int n_in,
                              void* d_out, int out_size, void* d_ws, size_t ws_size,
                              hipStream_t stream) {
    const float* in = (const float*)d_in[0];
    const float* wt = (const float*)d_in[1];
    float* out = (float*)d_out;

    const int B = in_sizes[0] / (3 * HDIM * WDIM);   // 8
    dim3 grid(4, 14, B * (NCOL / CPB));              // 4*14*40 = 2240 blocks
    rgb_conv2d_kernel<<<grid, dim3(256), 0, stream>>>(in, wt, out);
}

// Round 3
// 22.863 us; speedup vs baseline: 1.6181x; 1.0664x over previous
//
#include <hip/hip_runtime.h>
#include <math.h>

#define HDIM 224
#define WDIM 224
#define OH 220
#define OW 220
#define NCOL 30
#define TY 32              // output rows per tile
#define DROWS 36           // TY + 4
#define LSTR 228           // LDS row stride in words (224 + 4 pad; 57 float4s)
#define NF4 (DROWS * 57)   // 2052 float4 cells in the D tile
#define NORM_INV (1.0f / (25.0f * 768.0f))

__device__ __forceinline__ float4 ld4(const float* p) {
    return *reinterpret_cast<const float4*>(p);
}

__global__ __launch_bounds__(256) void rgb_conv2d_kernel(
    const float* __restrict__ in,   // [B,3,224,224]
    const float* __restrict__ wt,   // [30,3,5,5] (color constant over window)
    float* __restrict__ out)        // [B,30,220,220]
{
    __shared__ float Dd[DROWS * LSTR];   // 32832 B

    const int tid = threadIdx.x;
    const int by  = blockIdx.x;          // 0..6
    const int bc  = blockIdx.y;          // b*30 + c
    const int y0  = (by < 6) ? by * TY : (OH - TY);   // {0,32,...,160,188}
    const int b   = bc / NCOL;
    const int c   = bc - b * NCOL;

    const float* inb = in + (size_t)b * 3 * HDIM * WDIM;
    const float R2 = wt[c * 75 +  0] * 255.0f;
    const float G2 = wt[c * 75 + 25] * 255.0f;
    const float B2 = wt[c * 75 + 50] * 255.0f;
    // d^2 = cR*dR^2 + (2dG)^2 + cB*dB^2 + eps, 255-scaling folded into fma consts
    const float kR  = fmaf(R2, 1.0f / 512.0f, 2.0f);
    const float CC  = 4.0f + 255.0f / 256.0f;
    const float mR2 = -R2, mG2 = -2.0f * G2, mB2 = -B2;

    auto dist = [&](float pr, float pg, float pb) -> float {
        float dR  = fmaf(pr, 255.0f, mR2);
        float cR  = fmaf(pr, 255.0f / 512.0f, kR);
        float cB  = CC - cR;
        float dG2 = fmaf(pg, 510.0f, mG2);
        float dB  = fmaf(pb, 255.0f, mB2);
        float s   = fmaf(cR * dR, dR, 1e-8f);
        s = fmaf(dG2, dG2, s);
        s = fmaf(cB * dB, dB, s);
        return __builtin_amdgcn_sqrtf(s);
    };

    // ---- Pass 1: per-pixel distance tile, float4 granularity, full row width
    #pragma unroll
    for (int p = 0; p < 9; ++p) {
        int idx = tid + p * 256;
        if (idx < NF4) {
            int row  = idx / 57;
            int col4 = idx - row * 57;
            int pc   = min(col4, 55);          // col4==56 is LDS pad, clamp load
            const float* src = inb + (y0 + row) * WDIM + 4 * pc;
            float4 Pr = ld4(src);
            float4 Pg = ld4(src + HDIM * WDIM);
            float4 Pb = ld4(src + 2 * HDIM * WDIM);
            float4 dq;
            dq.x = dist(Pr.x, Pg.x, Pb.x);
            dq.y = dist(Pr.y, Pg.y, Pb.y);
            dq.z = dist(Pr.z, Pg.z, Pb.z);
            dq.w = dist(Pr.w, Pg.w, Pb.w);
            *reinterpret_cast<float4*>(&Dd[row * LSTR + 4 * col4]) = dq;
        }
    }
    __syncthreads();

    // ---- Pass 2: each thread owns a 4-wide x 8-tall output patch.
    // 4 outputs need D cols [4tx .. 4tx+7] = exactly 2 float4 reads per row.
    if (tid < 220) {
        const int tx = tid % 55;             // 0..54 -> output cols 4tx..4tx+3
        const int g  = tid / 55;             // 0..3  -> output rows 8g..8g+7
        const float* dp = &Dd[(8 * g) * LSTR + 4 * tx];
        float* ob = out + ((size_t)bc * OH + (y0 + 8 * g)) * OW + 4 * tx;

        float4 h[5];
        float4 o;
        #pragma unroll
        for (int r = 0; r < 12; ++r) {
            float4 A  = ld4(dp + r * LSTR);
            float4 Bv = ld4(dp + r * LSTR + 4);
            float h0 = ((A.x + A.y) + (A.z + A.w)) + Bv.x;
            float h1 = h0 + (Bv.y - A.x);
            float h2 = h1 + (Bv.z - A.y);
            float h3 = h2 + (Bv.w - A.z);
            float4 hr = make_float4(h0, h1, h2, h3);

            if (r < 4) {
                h[r] = hr;
            } else if (r == 4) {
                o.x = (((h[0].x + h[1].x) + (h[2].x + h[3].x)) + hr.x);
                o.y = (((h[0].y + h[1].y) + (h[2].y + h[3].y)) + hr.y);
                o.z = (((h[0].z + h[1].z) + (h[2].z + h[3].z)) + hr.z);
                o.w = (((h[0].w + h[1].w) + (h[2].w + h[3].w)) + hr.w);
                h[4] = hr;
                *reinterpret_cast<float4*>(ob) =
                    make_float4(o.x * NORM_INV, o.y * NORM_INV,
                                o.z * NORM_INV, o.w * NORM_INV);
            } else {
                float4 old = h[r % 5];       // row r-5 leaves the window
                o.x += hr.x - old.x;
                o.y += hr.y - old.y;
                o.z += hr.z - old.z;
                o.w += hr.w - old.w;
                h[r % 5] = hr;
                *reinterpret_cast<float4*>(ob + (r - 4) * OW) =
                    make_float4(o.x * NORM_INV, o.y * NORM_INV,
                                o.z * NORM_INV, o.w * NORM_INV);
            }
        }
    }
}

extern "C" void kernel_launch(void* const* d_in, const int* in_sizes, int n_in,
                              void* d_out, int out_size, void* d_ws, size_t ws_size,
                              hipStream_t stream) {
    const float* in = (const float*)d_in[0];
    const float* wt = (const float*)d_in[1];
    float* out = (float*)d_out;

    const int B = in_sizes[0] / (3 * HDIM * WDIM);   // 8
    dim3 grid(7, B * NCOL);                          // 7 y-tiles x 240 (b,c)
    rgb_conv2d_kernel<<<grid, dim3(256), 0, stream>>>(in, wt, out);
}